// Round 1
// baseline (3274.608 us; speedup 1.0000x reference)
//
#include <hip/hip_runtime.h>
#include <hip/hip_bf16.h>

#define N_NODES 50000
#define N_EDGES 400000
#define N_GRAPH 256
#define HID 256
#define DEPTH 6

typedef float f32x4 __attribute__((ext_vector_type(4)));
typedef int   i32x4 __attribute__((ext_vector_type(4)));

__device__ __forceinline__ float block_sum256(float v, float* lds) {
#pragma unroll
  for (int off = 32; off > 0; off >>= 1) v += __shfl_down(v, off, 64);
  int w = threadIdx.x >> 6;
  if ((threadIdx.x & 63) == 0) lds[w] = v;
  __syncthreads();
  float r = lds[0] + lds[1] + lds[2] + lds[3];
  __syncthreads();
  return r;
}

__global__ __launch_bounds__(256) void k_deg(const int* __restrict__ src, const int* __restrict__ dst,
                                             int* deg_out, int* deg_in) {
  int e = blockIdx.x * 256 + threadIdx.x;
  if (e < N_EDGES) { atomicAdd(&deg_out[src[e]], 1); atomicAdd(&deg_in[dst[e]], 1); }
}

__global__ __launch_bounds__(256) void k_norm(const int* deg_out, const int* deg_in,
                                              float* norm_o, float* norm_i) {
  int i = blockIdx.x * 256 + threadIdx.x;
  if (i < N_NODES) {
    int dO = deg_out[i], dI = deg_in[i];
    norm_o[i] = dO > 0 ? rsqrtf((float)dO) : 0.f;
    norm_i[i] = dI > 0 ? rsqrtf((float)dI) : 0.f;
  }
}

__global__ __launch_bounds__(256) void k_scan1(const int* deg_in, int* partial) {
  int i = blockIdx.x * 256 + threadIdx.x;
  int v = (i < N_NODES) ? deg_in[i] : 0;
#pragma unroll
  for (int off = 32; off > 0; off >>= 1) v += __shfl_down(v, off, 64);
  __shared__ int l[4];
  if ((threadIdx.x & 63) == 0) l[threadIdx.x >> 6] = v;
  __syncthreads();
  if (threadIdx.x == 0) partial[blockIdx.x] = l[0] + l[1] + l[2] + l[3];
}

__global__ __launch_bounds__(256) void k_scan2(const int* partial, int* chunk_off, int* row_start, int nb) {
  __shared__ int ss[256];
  int t = threadIdx.x;
  int v = (t < nb) ? partial[t] : 0;
  ss[t] = v; __syncthreads();
#pragma unroll
  for (int off = 1; off < 256; off <<= 1) {
    int x = ss[t];
    int y = (t >= off) ? ss[t - off] : 0;
    __syncthreads();
    ss[t] = x + y;
    __syncthreads();
  }
  if (t < nb) chunk_off[t] = ss[t] - v;      // exclusive chunk offset
  if (t == 0) row_start[N_NODES] = N_EDGES;  // sentinel
}

__global__ __launch_bounds__(256) void k_scan3(const int* deg_in, const int* chunk_off, int* row_start) {
  __shared__ int ss[256];
  int t = threadIdx.x;
  int i = blockIdx.x * 256 + t;
  int v = (i < N_NODES) ? deg_in[i] : 0;
  ss[t] = v; __syncthreads();
#pragma unroll
  for (int off = 1; off < 256; off <<= 1) {
    int x = ss[t];
    int y = (t >= off) ? ss[t - off] : 0;
    __syncthreads();
    ss[t] = x + y;
    __syncthreads();
  }
  if (i < N_NODES) row_start[i] = chunk_off[blockIdx.x] + ss[t] - v;
}

__global__ __launch_bounds__(256) void k_fill(const int* dst, const int* row_start, int* cursor, int* csr_eid) {
  int e = blockIdx.x * 256 + threadIdx.x;
  if (e < N_EDGES) {
    int d = dst[e];
    int p = atomicAdd(&cursor[d], 1);
    csr_eid[row_start[d] + p] = e;
  }
}

// Transpose + bf16-convert all 12 layer weights: Wt[li][n][k] = W[li][k][n]
__global__ __launch_bounds__(256) void k_wt(const float* __restrict__ Wc1, const float* __restrict__ Wc2,
                                            __hip_bfloat16* __restrict__ Wt) {
  __shared__ float tile[32][33];
  int li = blockIdx.z;
  const float* W = ((li & 1) ? Wc2 : Wc1) + (size_t)(li >> 1) * HID * HID;
  int k0 = blockIdx.x * 32, n0 = blockIdx.y * 32;
  int tx = threadIdx.x & 31, ty = threadIdx.x >> 5;
#pragma unroll
  for (int r = ty; r < 32; r += 8) tile[r][tx] = W[(size_t)(k0 + r) * HID + n0 + tx];
  __syncthreads();
  __hip_bfloat16* outp = Wt + (size_t)li * HID * HID;
#pragma unroll
  for (int r = ty; r < 32; r += 8) outp[(size_t)(n0 + r) * HID + k0 + tx] = __float2bfloat16(tile[tx][r]);
}

// y0 = (concat(a,c,x) @ W_in) * norm_o   (K=27, one block per node)
__global__ __launch_bounds__(256) void k_y0(const float* __restrict__ a, const float* __restrict__ c,
                                            const float* __restrict__ x, const float* __restrict__ norm_o,
                                            const float* __restrict__ W_in, float* __restrict__ y) {
  int n = blockIdx.x, ch = threadIdx.x;
  __shared__ float z[27];
  if (ch < 16) z[ch] = a[(size_t)n * 16 + ch];
  else if (ch < 24) z[ch] = c[(size_t)n * 8 + (ch - 16)];
  else if (ch < 27) z[ch] = x[(size_t)n * 3 + (ch - 24)];
  __syncthreads();
  float acc = 0.f;
#pragma unroll
  for (int k = 0; k < 27; ++k) acc += z[k] * W_in[k * HID + ch];
  y[(size_t)n * HID + ch] = acc * norm_o[n];
}

// h0 = agg(y0)*norm_i + b_in + ((sum_e e_t)@W_e + deg*b_e)/max(deg,1); emit hf + Af=bf16(h*norm_o)
__global__ __launch_bounds__(256) void k_h0(const float* __restrict__ y0, const float* __restrict__ e_t,
                                            const int* __restrict__ src, const int* __restrict__ csr,
                                            const int* __restrict__ rs, const float* __restrict__ norm_i,
                                            const float* __restrict__ norm_o, const float* __restrict__ b_in,
                                            const float* __restrict__ W_e, const float* __restrict__ b_e,
                                            float* __restrict__ hf, __hip_bfloat16* __restrict__ Af) {
  int n = blockIdx.x, ch = threadIdx.x;
  int beg = rs[n], end = rs[n + 1];
  float acc = 0.f;
  for (int p = beg; p < end; ++p) acc += y0[(size_t)src[csr[p]] * HID + ch];
  __shared__ float se[16];
  if (ch < 16) {
    float s = 0.f;
    for (int p = beg; p < end; ++p) s += e_t[(size_t)csr[p] * 16 + ch];
    se[ch] = s;
  }
  __syncthreads();
  float degf = (float)(end - beg);
  float invd = 1.f / fmaxf(degf, 1.f);
  float ec = degf * b_e[ch];
#pragma unroll
  for (int k = 0; k < 16; ++k) ec += se[k] * W_e[k * HID + ch];
  float h = acc * norm_i[n] + b_in[ch] + ec * invd;
  size_t idx = (size_t)n * HID + ch;
  hf[idx] = h;
  Af[idx] = __float2bfloat16(h * norm_o[n]);
}

// C[M,256] = Abf[M,256] @ W (via Wt[n][k]), bf16 MFMA 16x16x32 through inline asm.
__global__ __launch_bounds__(256) void k_gemm(const __hip_bfloat16* __restrict__ A,
                                              const __hip_bfloat16* __restrict__ Bt,
                                              float* __restrict__ C) {
  const int M = N_NODES;
  int wave = threadIdx.x >> 6;
  int lane = threadIdx.x & 63;
  int l15 = lane & 15;
  int quad = lane >> 4;
  int row0 = blockIdx.x * 64 + wave * 16;
  int n0 = blockIdx.y * 64;
  int arow = row0 + l15;
  if (arow > M - 1) arow = M - 1;  // clamp: OOB rows compute garbage, never stored
  const unsigned short* Au = (const unsigned short*)A;
  const unsigned short* Bu = (const unsigned short*)Bt;
  const unsigned short* ap = Au + (size_t)arow * HID + quad * 8;
  const unsigned short* bp = Bu + (size_t)(n0 + l15) * HID + quad * 8;
  f32x4 acc[4] = {};
  // hazard pad: VALU zero-init -> MFMA SrcC read
  asm volatile("s_nop 7\n\ts_nop 7" : "+v"(acc[0]), "+v"(acc[1]), "+v"(acc[2]), "+v"(acc[3]));
#pragma unroll
  for (int k0 = 0; k0 < HID; k0 += 32) {
    i32x4 af = *(const i32x4*)(ap + k0);
    i32x4 b0 = *(const i32x4*)(bp + k0);
    i32x4 b1 = *(const i32x4*)(bp + 16 * HID + k0);
    i32x4 b2 = *(const i32x4*)(bp + 32 * HID + k0);
    i32x4 b3 = *(const i32x4*)(bp + 48 * HID + k0);
    asm volatile("v_mfma_f32_16x16x32_bf16 %0, %1, %2, %0" : "+v"(acc[0]) : "v"(af), "v"(b0));
    asm volatile("v_mfma_f32_16x16x32_bf16 %0, %1, %2, %0" : "+v"(acc[1]) : "v"(af), "v"(b1));
    asm volatile("v_mfma_f32_16x16x32_bf16 %0, %1, %2, %0" : "+v"(acc[2]) : "v"(af), "v"(b2));
    asm volatile("v_mfma_f32_16x16x32_bf16 %0, %1, %2, %0" : "+v"(acc[3]) : "v"(af), "v"(b3));
  }
  // hazard pad: MFMA D write -> VMEM/VALU read of acc
  asm volatile("s_nop 7\n\ts_nop 7\n\ts_nop 7" : "+v"(acc[0]), "+v"(acc[1]), "+v"(acc[2]), "+v"(acc[3]));
#pragma unroll
  for (int j = 0; j < 4; ++j) {
    int r = row0 + quad * 4 + j;  // C/D layout: col = lane&15, row = quad*4 + reg
    if (r < M) {
      float* crow = C + (size_t)r * HID + n0 + l15;
      crow[0]  = acc[0][j];
      crow[16] = acc[1][j];
      crow[32] = acc[2][j];
      crow[48] = acc[3][j];
    }
  }
}

// fused: CSR gather-sum of y, *norm_i + b, LayerNorm(g,be), SiLU, (+residual -> hf), Af=bf16(out*norm_o)
template <int RES>
__global__ __launch_bounds__(256) void k_agg(const float* __restrict__ y, const int* __restrict__ src,
                                             const int* __restrict__ csr, const int* __restrict__ rs,
                                             const float* __restrict__ norm_i, const float* __restrict__ norm_o,
                                             const float* __restrict__ b, const float* __restrict__ g,
                                             const float* __restrict__ be, float* __restrict__ hf,
                                             __hip_bfloat16* __restrict__ Af) {
  int n = blockIdx.x, ch = threadIdx.x;
  int beg = rs[n], end = rs[n + 1];
  float acc = 0.f;
  for (int p = beg; p < end; ++p) acc += y[(size_t)src[csr[p]] * HID + ch];
  float val = acc * norm_i[n] + b[ch];
  __shared__ float l1[4], l2[4];
  float s1 = block_sum256(val, l1);
  float s2 = block_sum256(val * val, l2);
  float mu = s1 * (1.f / HID);
  float var = s2 * (1.f / HID) - mu * mu;
  float xn = (val - mu) * rsqrtf(var + 1e-5f);
  float o = xn * g[ch] + be[ch];
  float sl = o * (1.f / (1.f + expf(-o)));  // SiLU
  size_t idx = (size_t)n * HID + ch;
  float outv = sl;
  if (RES) { outv = sl + hf[idx]; hf[idx] = outv; }
  Af[idx] = __float2bfloat16(outv * norm_o[n]);
}

__global__ __launch_bounds__(256) void k_pool(const float* __restrict__ hf, const int* __restrict__ gid,
                                              float* pooled, int* cnt) {
  int n = blockIdx.x, ch = threadIdx.x;
  int gg = gid[n];
  atomicAdd(&pooled[(size_t)gg * HID + ch], hf[(size_t)n * HID + ch]);
  if (ch == 0) atomicAdd(&cnt[gg], 1);
}

__global__ __launch_bounds__(256) void k_head(const float* __restrict__ pooled, const int* __restrict__ cnt,
                                              const float* __restrict__ Wh, const float* __restrict__ bh,
                                              float* __restrict__ out) {
  int gg = blockIdx.x, ch = threadIdx.x;
  float v = pooled[(size_t)gg * HID + ch] * Wh[ch];
  __shared__ float l[4];
  float s = block_sum256(v, l);
  if (ch == 0) {
    float c = fmaxf((float)cnt[gg], 1.f);
    float xx = s / c + bh[0];
    out[gg] = fmaxf(xx, 0.f) + log1pf(expf(-fabsf(xx)));  // stable softplus
  }
}

extern "C" void kernel_launch(void* const* d_in, const int* in_sizes, int n_in,
                              void* d_out, int out_size, void* d_ws, size_t ws_size,
                              hipStream_t stream) {
  const float* a_t = (const float*)d_in[0];
  const float* c_t = (const float*)d_in[1];
  const float* x_t = (const float*)d_in[2];
  const float* e_t = (const float*)d_in[3];
  const int* src = (const int*)d_in[4];
  const int* dst = (const int*)d_in[5];
  const int* gid = (const int*)d_in[6];
  const float* W_in = (const float*)d_in[7];
  const float* b_in = (const float*)d_in[8];
  const float* W_e  = (const float*)d_in[9];
  const float* b_e  = (const float*)d_in[10];
  const float* Wc1  = (const float*)d_in[11];
  const float* bc1  = (const float*)d_in[12];
  const float* g1   = (const float*)d_in[13];
  const float* be1  = (const float*)d_in[14];
  const float* Wc2  = (const float*)d_in[15];
  const float* bc2  = (const float*)d_in[16];
  const float* g2   = (const float*)d_in[17];
  const float* be2  = (const float*)d_in[18];
  const float* W_head = (const float*)d_in[19];
  const float* b_head = (const float*)d_in[20];
  float* out = (float*)d_out;

  // ---- workspace carve (needs ~133 MB) ----
  char* base = (char*)d_ws;
  size_t off = 0;
  auto carve = [&](size_t bytes) -> void* {
    void* p = base + off;
    off += (bytes + 255) & ~(size_t)255;
    return p;
  };
  int*   deg_out = (int*)carve((size_t)N_NODES * 4);
  int*   deg_in  = (int*)carve((size_t)N_NODES * 4);
  int*   cursor  = (int*)carve((size_t)N_NODES * 4);
  int*   cnt     = (int*)carve((size_t)N_GRAPH * 4);
  float* pooled  = (float*)carve((size_t)N_GRAPH * HID * 4);
  size_t zbytes = off;  // everything above is zeroed each call
  float* norm_o  = (float*)carve((size_t)N_NODES * 4);
  float* norm_i  = (float*)carve((size_t)N_NODES * 4);
  int*   row_start = (int*)carve((size_t)(N_NODES + 1) * 4);
  int*   partial   = (int*)carve(256 * 4);
  int*   chunk_off = (int*)carve(256 * 4);
  int*   csr_eid   = (int*)carve((size_t)N_EDGES * 4);
  __hip_bfloat16* Wt = (__hip_bfloat16*)carve((size_t)2 * DEPTH * HID * HID * 2);
  float* y  = (float*)carve((size_t)N_NODES * HID * 4);
  float* hf = (float*)carve((size_t)N_NODES * HID * 4);
  __hip_bfloat16* Af = (__hip_bfloat16*)carve((size_t)N_NODES * HID * 2);
  (void)ws_size; (void)in_sizes; (void)n_in; (void)out_size;

  hipMemsetAsync(d_ws, 0, zbytes, stream);

  int ebl = (N_EDGES + 255) / 256;
  int nbl = (N_NODES + 255) / 256;  // 196
  k_deg<<<ebl, 256, 0, stream>>>(src, dst, deg_out, deg_in);
  k_norm<<<nbl, 256, 0, stream>>>(deg_out, deg_in, norm_o, norm_i);
  k_scan1<<<nbl, 256, 0, stream>>>(deg_in, partial);
  k_scan2<<<1, 256, 0, stream>>>(partial, chunk_off, row_start, nbl);
  k_scan3<<<nbl, 256, 0, stream>>>(deg_in, chunk_off, row_start);
  k_fill<<<ebl, 256, 0, stream>>>(dst, row_start, cursor, csr_eid);
  k_wt<<<dim3(8, 8, 2 * DEPTH), 256, 0, stream>>>(Wc1, Wc2, Wt);
  k_y0<<<N_NODES, 256, 0, stream>>>(a_t, c_t, x_t, norm_o, W_in, y);
  k_h0<<<N_NODES, 256, 0, stream>>>(y, e_t, src, csr_eid, row_start, norm_i, norm_o,
                                    b_in, W_e, b_e, hf, Af);
  dim3 ggrid((N_NODES + 63) / 64, HID / 64);
  for (int d = 0; d < DEPTH; ++d) {
    k_gemm<<<ggrid, 256, 0, stream>>>(Af, Wt + (size_t)(2 * d) * HID * HID, y);
    k_agg<0><<<N_NODES, 256, 0, stream>>>(y, src, csr_eid, row_start, norm_i, norm_o,
                                          bc1 + d * HID, g1 + d * HID, be1 + d * HID, hf, Af);
    k_gemm<<<ggrid, 256, 0, stream>>>(Af, Wt + (size_t)(2 * d + 1) * HID * HID, y);
    k_agg<1><<<N_NODES, 256, 0, stream>>>(y, src, csr_eid, row_start, norm_i, norm_o,
                                          bc2 + d * HID, g2 + d * HID, be2 + d * HID, hf, Af);
  }
  k_pool<<<N_NODES, 256, 0, stream>>>(hf, gid, pooled, cnt);
  k_head<<<N_GRAPH, 256, 0, stream>>>(pooled, cnt, W_head, b_head, out);
}

// Round 2
// 2017.549 us; speedup vs baseline: 1.6231x; 1.6231x over previous
//
#include <hip/hip_runtime.h>
#include <hip/hip_bf16.h>

#define N_NODES 50000
#define N_EDGES 400000
#define N_GRAPH 256
#define HID 256
#define DEPTH 6

typedef float f32x4 __attribute__((ext_vector_type(4)));
typedef int   i32x4 __attribute__((ext_vector_type(4)));

__device__ __forceinline__ float bf2f(unsigned short u) {
  unsigned v = ((unsigned)u) << 16;
  return __builtin_bit_cast(float, v);
}
__device__ __forceinline__ unsigned short f2bf(float f) {
  unsigned u = __builtin_bit_cast(unsigned, f);
  u += 0x7fffu + ((u >> 16) & 1u);  // RNE
  return (unsigned short)(u >> 16);
}

__device__ __forceinline__ float block_sum256(float v, float* lds) {
#pragma unroll
  for (int off = 32; off > 0; off >>= 1) v += __shfl_down(v, off, 64);
  int w = threadIdx.x >> 6;
  if ((threadIdx.x & 63) == 0) lds[w] = v;
  __syncthreads();
  float r = lds[0] + lds[1] + lds[2] + lds[3];
  __syncthreads();
  return r;
}

__global__ __launch_bounds__(256) void k_deg(const int* __restrict__ src, const int* __restrict__ dst,
                                             int* deg_out, int* deg_in) {
  int e = blockIdx.x * 256 + threadIdx.x;
  if (e < N_EDGES) { atomicAdd(&deg_out[src[e]], 1); atomicAdd(&deg_in[dst[e]], 1); }
}

__global__ __launch_bounds__(256) void k_norm(const int* deg_out, const int* deg_in,
                                              float* norm_o, float* norm_i) {
  int i = blockIdx.x * 256 + threadIdx.x;
  if (i < N_NODES) {
    int dO = deg_out[i], dI = deg_in[i];
    norm_o[i] = dO > 0 ? rsqrtf((float)dO) : 0.f;
    norm_i[i] = dI > 0 ? rsqrtf((float)dI) : 0.f;
  }
}

__global__ __launch_bounds__(256) void k_scan1(const int* deg_in, int* partial) {
  int i = blockIdx.x * 256 + threadIdx.x;
  int v = (i < N_NODES) ? deg_in[i] : 0;
#pragma unroll
  for (int off = 32; off > 0; off >>= 1) v += __shfl_down(v, off, 64);
  __shared__ int l[4];
  if ((threadIdx.x & 63) == 0) l[threadIdx.x >> 6] = v;
  __syncthreads();
  if (threadIdx.x == 0) partial[blockIdx.x] = l[0] + l[1] + l[2] + l[3];
}

__global__ __launch_bounds__(256) void k_scan2(const int* partial, int* chunk_off, int* row_start, int nb) {
  __shared__ int ss[256];
  int t = threadIdx.x;
  int v = (t < nb) ? partial[t] : 0;
  ss[t] = v; __syncthreads();
#pragma unroll
  for (int off = 1; off < 256; off <<= 1) {
    int x = ss[t];
    int y = (t >= off) ? ss[t - off] : 0;
    __syncthreads();
    ss[t] = x + y;
    __syncthreads();
  }
  if (t < nb) chunk_off[t] = ss[t] - v;
  if (t == 0) row_start[N_NODES] = N_EDGES;
}

__global__ __launch_bounds__(256) void k_scan3(const int* deg_in, const int* chunk_off, int* row_start) {
  __shared__ int ss[256];
  int t = threadIdx.x;
  int i = blockIdx.x * 256 + t;
  int v = (i < N_NODES) ? deg_in[i] : 0;
  ss[t] = v; __syncthreads();
#pragma unroll
  for (int off = 1; off < 256; off <<= 1) {
    int x = ss[t];
    int y = (t >= off) ? ss[t - off] : 0;
    __syncthreads();
    ss[t] = x + y;
    __syncthreads();
  }
  if (i < N_NODES) row_start[i] = chunk_off[blockIdx.x] + ss[t] - v;
}

__global__ __launch_bounds__(256) void k_fill(const int* src, const int* dst, const int* row_start,
                                              int* cursor, int* csr_src, int* csr_eid) {
  int e = blockIdx.x * 256 + threadIdx.x;
  if (e < N_EDGES) {
    int d = dst[e];
    int p = atomicAdd(&cursor[d], 1);
    int pos = row_start[d] + p;
    csr_src[pos] = src[e];
    csr_eid[pos] = e;
  }
}

// Transpose + bf16-convert all 12 layer weights: Wt[li][n][k] = W[li][k][n]
__global__ __launch_bounds__(256) void k_wt(const float* __restrict__ Wc1, const float* __restrict__ Wc2,
                                            unsigned short* __restrict__ Wt) {
  __shared__ float tile[32][33];
  int li = blockIdx.z;
  const float* W = ((li & 1) ? Wc2 : Wc1) + (size_t)(li >> 1) * HID * HID;
  int k0 = blockIdx.x * 32, n0 = blockIdx.y * 32;
  int tx = threadIdx.x & 31, ty = threadIdx.x >> 5;
#pragma unroll
  for (int r = ty; r < 32; r += 8) tile[r][tx] = W[(size_t)(k0 + r) * HID + n0 + tx];
  __syncthreads();
  unsigned short* outp = Wt + (size_t)li * HID * HID;
#pragma unroll
  for (int r = ty; r < 32; r += 8) outp[(size_t)(n0 + r) * HID + k0 + tx] = f2bf(tile[tx][r]);
}

// Input layer fused: aggregate 27-dim src-normalized feats + 16-dim edge feats per node,
// K=43 dot with W_in/W_e, produce hf (f32 residual stream) and Af (bf16 next-A).
__global__ __launch_bounds__(256) void k_in(const float* __restrict__ a, const float* __restrict__ c,
                                            const float* __restrict__ x, const float* __restrict__ e_t,
                                            const int* __restrict__ csr_src, const int* __restrict__ csr_eid,
                                            const int* __restrict__ rs, const float* __restrict__ norm_o,
                                            const float* __restrict__ norm_i, const float* __restrict__ W_in,
                                            const float* __restrict__ b_in, const float* __restrict__ W_e,
                                            const float* __restrict__ b_e, float* __restrict__ hf,
                                            unsigned short* __restrict__ Af) {
  int w = threadIdx.x >> 6, lane = threadIdx.x & 63;
  int n = blockIdx.x * 4 + w;  // 50000 % 4 == 0, no guard needed
  __shared__ float z[4][43];
  int beg = rs[n], end = rs[n + 1];
  float acc = 0.f;
  for (int p = beg; p < end; ++p) {
    int s = csr_src[p];
    if (lane < 27) {
      float no = norm_o[s];
      float v = lane < 16 ? a[(size_t)s * 16 + lane]
              : (lane < 24 ? c[(size_t)s * 8 + (lane - 16)]
                           : x[(size_t)s * 3 + (lane - 24)]);
      acc += v * no;
    } else if (lane < 43) {
      acc += e_t[(size_t)csr_eid[p] * 16 + (lane - 27)];
    }
  }
  if (lane < 43) z[w][lane] = acc;
  __syncthreads();
  float degf = (float)(end - beg);
  float invd = 1.f / fmaxf(degf, 1.f);
  float niv = norm_i[n], nov = norm_o[n];
#pragma unroll
  for (int i = 0; i < 4; ++i) {
    int ch = lane + 64 * i;
    float da = 0.f, de = 0.f;
#pragma unroll
    for (int k = 0; k < 27; ++k) da += z[w][k] * W_in[k * HID + ch];
#pragma unroll
    for (int k = 0; k < 16; ++k) de += z[w][27 + k] * W_e[k * HID + ch];
    float val = da * niv + b_in[ch] + (de + degf * b_e[ch]) * invd;
    hf[(size_t)n * HID + ch] = val;
    Af[(size_t)n * HID + ch] = f2bf(val * nov);
  }
}

// Gather-aggregate bf16 A rows: Ag[n] = bf16(sum_{p in row n} Af[csr_src[p]])
// wave per node, 8B/lane vector loads, 4-edge unroll for MLP.
__global__ __launch_bounds__(256) void k_gath(const unsigned short* __restrict__ Af,
                                              const int* __restrict__ csr_src, const int* __restrict__ rs,
                                              unsigned short* __restrict__ Ag) {
  int w = threadIdx.x >> 6, lane = threadIdx.x & 63;
  int n = blockIdx.x * 4 + w;
  int beg = rs[n], end = rs[n + 1];
  int off = lane * 4;
  float a0 = 0.f, a1 = 0.f, a2 = 0.f, a3 = 0.f;
  int p = beg;
  for (; p + 4 <= end; p += 4) {
    int s0 = csr_src[p], s1 = csr_src[p + 1], s2 = csr_src[p + 2], s3 = csr_src[p + 3];
    ushort4 r0 = *(const ushort4*)(Af + (size_t)s0 * HID + off);
    ushort4 r1 = *(const ushort4*)(Af + (size_t)s1 * HID + off);
    ushort4 r2 = *(const ushort4*)(Af + (size_t)s2 * HID + off);
    ushort4 r3 = *(const ushort4*)(Af + (size_t)s3 * HID + off);
    a0 += bf2f(r0.x) + bf2f(r1.x) + bf2f(r2.x) + bf2f(r3.x);
    a1 += bf2f(r0.y) + bf2f(r1.y) + bf2f(r2.y) + bf2f(r3.y);
    a2 += bf2f(r0.z) + bf2f(r1.z) + bf2f(r2.z) + bf2f(r3.z);
    a3 += bf2f(r0.w) + bf2f(r1.w) + bf2f(r2.w) + bf2f(r3.w);
  }
  for (; p < end; ++p) {
    int s0 = csr_src[p];
    ushort4 r0 = *(const ushort4*)(Af + (size_t)s0 * HID + off);
    a0 += bf2f(r0.x); a1 += bf2f(r0.y); a2 += bf2f(r0.z); a3 += bf2f(r0.w);
  }
  ushort4 o;
  o.x = f2bf(a0); o.y = f2bf(a1); o.z = f2bf(a2); o.w = f2bf(a3);
  *(ushort4*)(Ag + (size_t)n * HID + off) = o;
}

// GEMM [M,256]@[256,256] with fused epilogue:
// val = (Ag@W)*norm_i + b; LN(g,be); SiLU; (+= hf residual if RES); Af_next = bf16(out*norm_o)
template <int RES>
__global__ __launch_bounds__(256) void k_gemm2(const unsigned short* __restrict__ Ag,
                                               const unsigned short* __restrict__ Bt,
                                               const float* __restrict__ norm_i,
                                               const float* __restrict__ norm_o,
                                               const float* __restrict__ b, const float* __restrict__ g,
                                               const float* __restrict__ be, float* __restrict__ hf,
                                               unsigned short* __restrict__ AfN) {
  const int M = N_NODES;
  int wave = threadIdx.x >> 6, lane = threadIdx.x & 63;
  int l15 = lane & 15, quad = lane >> 4;
  int row0 = blockIdx.x * 64 + wave * 16;
  int arow = row0 + l15;
  if (arow > M - 1) arow = M - 1;  // OOB rows compute garbage, never stored
  const unsigned short* ap = Ag + (size_t)arow * HID + quad * 8;
  const unsigned short* bp = Bt + (size_t)l15 * HID + quad * 8;
  f32x4 acc[16] = {};
  asm volatile("s_nop 7\n\ts_nop 7"
               : "+v"(acc[0]), "+v"(acc[1]), "+v"(acc[2]), "+v"(acc[3]),
                 "+v"(acc[4]), "+v"(acc[5]), "+v"(acc[6]), "+v"(acc[7]),
                 "+v"(acc[8]), "+v"(acc[9]), "+v"(acc[10]), "+v"(acc[11]),
                 "+v"(acc[12]), "+v"(acc[13]), "+v"(acc[14]), "+v"(acc[15]));
#pragma unroll
  for (int k0 = 0; k0 < HID; k0 += 32) {
    i32x4 af = *(const i32x4*)(ap + k0);
#pragma unroll
    for (int t = 0; t < 16; ++t) {
      i32x4 bt = *(const i32x4*)(bp + (size_t)t * 16 * HID + k0);
      asm volatile("v_mfma_f32_16x16x32_bf16 %0, %1, %2, %0" : "+v"(acc[t]) : "v"(af), "v"(bt));
    }
  }
  asm volatile("s_nop 7\n\ts_nop 7\n\ts_nop 7"
               : "+v"(acc[0]), "+v"(acc[1]), "+v"(acc[2]), "+v"(acc[3]),
                 "+v"(acc[4]), "+v"(acc[5]), "+v"(acc[6]), "+v"(acc[7]),
                 "+v"(acc[8]), "+v"(acc[9]), "+v"(acc[10]), "+v"(acc[11]),
                 "+v"(acc[12]), "+v"(acc[13]), "+v"(acc[14]), "+v"(acc[15]));
  // epilogue: rows r = row0 + quad*4 + j, cols ct = t*16 + l15
  float ni[4], no[4];
#pragma unroll
  for (int j = 0; j < 4; ++j) {
    int r = row0 + quad * 4 + j;
    int rc = r < M ? r : M - 1;
    ni[j] = norm_i[rc];
    no[j] = norm_o[rc];
  }
#pragma unroll
  for (int t = 0; t < 16; ++t) {
    int ct = t * 16 + l15;
    float bv = b[ct];
#pragma unroll
    for (int j = 0; j < 4; ++j) acc[t][j] = acc[t][j] * ni[j] + bv;
  }
  float s1[4] = {0.f, 0.f, 0.f, 0.f}, s2[4] = {0.f, 0.f, 0.f, 0.f};
#pragma unroll
  for (int t = 0; t < 16; ++t)
#pragma unroll
    for (int j = 0; j < 4; ++j) { s1[j] += acc[t][j]; s2[j] += acc[t][j] * acc[t][j]; }
#pragma unroll
  for (int m = 1; m < 16; m <<= 1) {
#pragma unroll
    for (int j = 0; j < 4; ++j) {
      s1[j] += __shfl_xor(s1[j], m, 16);
      s2[j] += __shfl_xor(s2[j], m, 16);
    }
  }
  float mu[4], inv[4];
#pragma unroll
  for (int j = 0; j < 4; ++j) {
    mu[j] = s1[j] * (1.f / HID);
    float var = s2[j] * (1.f / HID) - mu[j] * mu[j];
    inv[j] = rsqrtf(var + 1e-5f);
  }
#pragma unroll
  for (int j = 0; j < 4; ++j) {
    int r = row0 + quad * 4 + j;
    if (r < M) {
      float* hrow = hf + (size_t)r * HID;
      unsigned short* an = AfN + (size_t)r * HID;
#pragma unroll
      for (int t = 0; t < 16; ++t) {
        int ct = t * 16 + l15;
        float o = (acc[t][j] - mu[j]) * inv[j] * g[ct] + be[ct];
        float sl = o * (1.f / (1.f + __expf(-o)));
        float outv = sl;
        if (RES) {
          outv = sl + hrow[ct];
          hrow[ct] = outv;
        }
        an[ct] = f2bf(outv * no[j]);
      }
    }
  }
}

__global__ __launch_bounds__(256) void k_pool(const float* __restrict__ hf, const int* __restrict__ gid,
                                              float* pooled, int* cnt) {
  int n = blockIdx.x, ch = threadIdx.x;
  int gg = gid[n];
  atomicAdd(&pooled[(size_t)gg * HID + ch], hf[(size_t)n * HID + ch]);
  if (ch == 0) atomicAdd(&cnt[gg], 1);
}

__global__ __launch_bounds__(256) void k_head(const float* __restrict__ pooled, const int* __restrict__ cnt,
                                              const float* __restrict__ Wh, const float* __restrict__ bh,
                                              float* __restrict__ out) {
  int gg = blockIdx.x, ch = threadIdx.x;
  float v = pooled[(size_t)gg * HID + ch] * Wh[ch];
  __shared__ float l[4];
  float s = block_sum256(v, l);
  if (ch == 0) {
    float c = fmaxf((float)cnt[gg], 1.f);
    float xx = s / c + bh[0];
    out[gg] = fmaxf(xx, 0.f) + log1pf(expf(-fabsf(xx)));  // stable softplus
  }
}

extern "C" void kernel_launch(void* const* d_in, const int* in_sizes, int n_in,
                              void* d_out, int out_size, void* d_ws, size_t ws_size,
                              hipStream_t stream) {
  const float* a_t = (const float*)d_in[0];
  const float* c_t = (const float*)d_in[1];
  const float* x_t = (const float*)d_in[2];
  const float* e_t = (const float*)d_in[3];
  const int* src = (const int*)d_in[4];
  const int* dst = (const int*)d_in[5];
  const int* gid = (const int*)d_in[6];
  const float* W_in = (const float*)d_in[7];
  const float* b_in = (const float*)d_in[8];
  const float* W_e  = (const float*)d_in[9];
  const float* b_e  = (const float*)d_in[10];
  const float* Wc1  = (const float*)d_in[11];
  const float* bc1  = (const float*)d_in[12];
  const float* g1   = (const float*)d_in[13];
  const float* be1  = (const float*)d_in[14];
  const float* Wc2  = (const float*)d_in[15];
  const float* bc2  = (const float*)d_in[16];
  const float* g2   = (const float*)d_in[17];
  const float* be2  = (const float*)d_in[18];
  const float* W_head = (const float*)d_in[19];
  const float* b_head = (const float*)d_in[20];
  float* out = (float*)d_out;

  char* base = (char*)d_ws;
  size_t off = 0;
  auto carve = [&](size_t bytes) -> void* {
    void* p = base + off;
    off += (bytes + 255) & ~(size_t)255;
    return p;
  };
  int*   deg_out = (int*)carve((size_t)N_NODES * 4);
  int*   deg_in  = (int*)carve((size_t)N_NODES * 4);
  int*   cursor  = (int*)carve((size_t)N_NODES * 4);
  int*   cnt     = (int*)carve((size_t)N_GRAPH * 4);
  float* pooled  = (float*)carve((size_t)N_GRAPH * HID * 4);
  size_t zbytes = off;  // zeroed each call
  float* norm_o  = (float*)carve((size_t)N_NODES * 4);
  float* norm_i  = (float*)carve((size_t)N_NODES * 4);
  int*   row_start = (int*)carve((size_t)(N_NODES + 1) * 4);
  int*   partial   = (int*)carve(256 * 4);
  int*   chunk_off = (int*)carve(256 * 4);
  int*   csr_src   = (int*)carve((size_t)N_EDGES * 4);
  int*   csr_eid   = (int*)carve((size_t)N_EDGES * 4);
  unsigned short* Wt = (unsigned short*)carve((size_t)2 * DEPTH * HID * HID * 2);
  float* hf = (float*)carve((size_t)N_NODES * HID * 4);
  unsigned short* Af = (unsigned short*)carve((size_t)N_NODES * HID * 2);
  unsigned short* Ag = (unsigned short*)carve((size_t)N_NODES * HID * 2);
  (void)ws_size; (void)in_sizes; (void)n_in; (void)out_size;

  hipMemsetAsync(d_ws, 0, zbytes, stream);

  int ebl = (N_EDGES + 255) / 256;
  int nbl = (N_NODES + 255) / 256;
  k_deg<<<ebl, 256, 0, stream>>>(src, dst, deg_out, deg_in);
  k_norm<<<nbl, 256, 0, stream>>>(deg_out, deg_in, norm_o, norm_i);
  k_scan1<<<nbl, 256, 0, stream>>>(deg_in, partial);
  k_scan2<<<1, 256, 0, stream>>>(partial, chunk_off, row_start, nbl);
  k_scan3<<<nbl, 256, 0, stream>>>(deg_in, chunk_off, row_start);
  k_fill<<<ebl, 256, 0, stream>>>(src, dst, row_start, cursor, csr_src, csr_eid);
  k_wt<<<dim3(8, 8, 2 * DEPTH), 256, 0, stream>>>(Wc1, Wc2, Wt);
  k_in<<<N_NODES / 4, 256, 0, stream>>>(a_t, c_t, x_t, e_t, csr_src, csr_eid, row_start,
                                        norm_o, norm_i, W_in, b_in, W_e, b_e, hf, Af);
  int gbl = (N_NODES + 63) / 64;  // 782
  for (int d = 0; d < DEPTH; ++d) {
    k_gath<<<N_NODES / 4, 256, 0, stream>>>(Af, csr_src, row_start, Ag);
    k_gemm2<0><<<gbl, 256, 0, stream>>>(Ag, Wt + (size_t)(2 * d) * HID * HID, norm_i, norm_o,
                                        bc1 + d * HID, g1 + d * HID, be1 + d * HID, hf, Af);
    k_gath<<<N_NODES / 4, 256, 0, stream>>>(Af, csr_src, row_start, Ag);
    k_gemm2<1><<<gbl, 256, 0, stream>>>(Ag, Wt + (size_t)(2 * d + 1) * HID * HID, norm_i, norm_o,
                                        bc2 + d * HID, g2 + d * HID, be2 + d * HID, hf, Af);
  }
  k_pool<<<N_NODES, 256, 0, stream>>>(hf, gid, pooled, cnt);
  k_head<<<N_GRAPH, 256, 0, stream>>>(pooled, cnt, W_head, b_head, out);
}